// Round 13
// baseline (2101.084 us; speedup 1.0000x reference)
//
#include <hip/hip_runtime.h>

#define EMBD 256
#define HIDD 512
#define SEQL 512

typedef unsigned int u32;
typedef unsigned long long u64;
typedef _Float16 half8 __attribute__((ext_vector_type(8)));
typedef _Float16 h2 __attribute__((ext_vector_type(2)));
typedef float f32x4 __attribute__((ext_vector_type(4)));

#define WS_WA_OFF 0                       // 786432 B : W A-frags [mt 0..31][chunk 0..23][64][4dw]
#define WS_XS_OFF 786432                  // 67108864 B : u64 xs[512 t][128 row][128] (f16 pairs, bias folded)
#define WS_NEED   (786432ull + 67108864ull)

static __device__ __forceinline__ u32 packh2(float a, float b) {
    _Float16 lo = (_Float16)a, hi = (_Float16)b;
    return (u32)__builtin_bit_cast(unsigned short, lo)
         | ((u32)__builtin_bit_cast(unsigned short, hi) << 16);
}

static __device__ __forceinline__ float fast_tanh(float x) {
    x = fminf(10.f, fmaxf(-10.f, x));
    const float e = __expf(2.f * x);
    return (e - 1.f) * __builtin_amdgcn_rcpf(e + 1.f);
}

// W (f32 [768][512]) -> A-frags for mfma_f32_16x16x32_f16.
// Frag (mt, c): lane l, dword d = f16 pair (k0,k0+1), k0 = 32c + 8*(l>>4) + 2d,
// hcol = mt*16 + (l&15). Grid 768 (= mt*24+c) x 256.   [verified R10-R12]
__global__ __launch_bounds__(256)
void convert_WA(const float* __restrict__ W, u32* __restrict__ WA) {
    const int b = blockIdx.x;
    const int mt = b / 24, c = b % 24;
    const int tid = threadIdx.x, l = tid >> 2, d = tid & 3;
    const int k0 = 32 * c + 8 * (l >> 4) + 2 * d;
    const int hc = mt * 16 + (l & 15);
    WA[b * 256 + tid] = packh2(W[(size_t)k0 * HIDD + hc],
                               W[(size_t)(k0 + 1) * HIDD + hc]);
}

// xs[t][row][hcol] = (emb(tok[row][t]) @ Wx)[hcol] + bias[hcol], f16 pairs. [verified R12]
__global__ __launch_bounds__(256)
void xproj_gemm(const int*   __restrict__ tokens,
                const float* __restrict__ V,
                const u32*   __restrict__ WA,
                const float* __restrict__ bias,
                u64*         __restrict__ XS)
{
    const int wgid = blockIdx.x;
    const int t = wgid >> 3, rb = wgid & 7;
    const int w = threadIdx.x >> 6, l = threadIdx.x & 63;
    const int g = l >> 4;
    const int row = rb * 16 + (l & 15);

    const int tok = tokens[row * SEQL + t];
    const float* vb = V + (size_t)tok * EMBD;
    uint4 eb[8];
    #pragma unroll
    for (int c = 0; c < 8; ++c) {
        const float4 v1 = *(const float4*)&vb[32 * c + 8 * g];
        const float4 v2 = *(const float4*)&vb[32 * c + 8 * g + 4];
        eb[c].x = packh2(v1.x, v1.y); eb[c].y = packh2(v1.z, v1.w);
        eb[c].z = packh2(v2.x, v2.y); eb[c].w = packh2(v2.z, v2.w);
    }
    #pragma unroll
    for (int i = 0; i < 8; ++i) {
        const int hcb = w * 8 + i;
        f32x4 acc = (f32x4){0.f, 0.f, 0.f, 0.f};
        #pragma unroll
        for (int c = 0; c < 8; ++c) {
            const uint4 a = *(const uint4*)&WA[((hcb * 24 + c) * 64 + l) * 4];
            acc = __builtin_amdgcn_mfma_f32_16x16x32_f16(
                __builtin_bit_cast(half8, a), __builtin_bit_cast(half8, eb[c]),
                acc, 0, 0, 0);
        }
        const float4 b4 = *(const float4*)&bias[hcb * 16 + 4 * g];
        const u64 pk = (u64)packh2(acc.x + b4.x, acc.y + b4.y)
                     | ((u64)packh2(acc.z + b4.z, acc.w + b4.w) << 32);
        XS[(size_t)t * 16384 + (size_t)row * 128 + hcb * 4 + g] = pk;
    }
}

// Fortress v2: 8 WGs (one ring = 16 rows each) x 256 thr (4 waves, 1/SIMD).
// Wave w: M-tiles w*8..w*8+7 (128 hcols), FULL K=512. Each B-frag read feeds
// 8 MFMAs. Wh: 13 chunks in 416 regs, 3 chunks in LDS. 1 barrier/step.
__global__ __launch_bounds__(256, 1)
void rnn_fort2(const u32*   __restrict__ WA,
               const u64*   __restrict__ XS,
               const float* __restrict__ Wd,
               const float* __restrict__ bd,
               float*       __restrict__ y)
{
    __shared__ uint4 Wlds[32][3][64];   // 96 KB : state chunks 13..15 per mt
    __shared__ uint4 Sst[2][16][64];    // 32 KB : state B-frags, dbuf
    __shared__ float yp[16][17];

    const int tid = threadIdx.x, ring = blockIdx.x;
    const int w = tid >> 6, l = tid & 63, g = l >> 4, r = l & 15;
    const int w8 = w * 8;

    // fill Wlds (WA chunks 21..23 = state chunks 13..15)
    for (int i = tid; i < 32 * 3 * 64; i += 256) {
        const int mt = i / 192, rem = i % 192, cl = rem >> 6, l2 = rem & 63;
        Wlds[mt][cl][l2] = *(const uint4*)&WA[((mt * 24 + 21 + cl) * 64 + l2) * 4];
    }
    // zero state buffers
    for (int i = tid; i < 2 * 16 * 64; i += 256)
        ((uint4*)Sst)[i] = (uint4){0u, 0u, 0u, 0u};

    // Wh register frags: state chunks 0..12 x 8 mt (416 regs, mostly AGPR)
    uint4 wreg[13][8];
    #pragma unroll
    for (int c = 0; c < 13; ++c)
        #pragma unroll
        for (int i = 0; i < 8; ++i)
            wreg[c][i] = *(const uint4*)&WA[(((w8 + i) * 24 + 8 + c) * 64 + l) * 4];

    const u64* XSb = XS + (size_t)(ring * 16 + r) * 128;
    __syncthreads();

    for (int t = 0; t < SEQL; ++t) {
        const int cur = t & 1, nxt = cur ^ 1;
        const u64* XSt = XSb + (size_t)t * 16384;

        f32x4 acc[8];
        #pragma unroll
        for (int i = 0; i < 8; ++i) acc[i] = (f32x4){0.f, 0.f, 0.f, 0.f};

        u64 xq[8];
        uint4 B = Sst[cur][0][l];

        #pragma unroll
        for (int c = 0; c < 16; ++c) {
            uint4 Bn;
            if (c < 15) Bn = Sst[cur][c + 1][l];
            if (c == 8) {   // issue xs loads mid-block (consumed in tail)
                #pragma unroll
                for (int i = 0; i < 8; ++i) xq[i] = XSt[(w8 + i) * 4 + g];
            }
            if (c < 13) {
                #pragma unroll
                for (int i = 0; i < 8; ++i)
                    acc[i] = __builtin_amdgcn_mfma_f32_16x16x32_f16(
                        __builtin_bit_cast(half8, wreg[c][i]),
                        __builtin_bit_cast(half8, B), acc[i], 0, 0, 0);
            } else {
                const int cl = c - 13;
                #pragma unroll
                for (int i = 0; i < 8; ++i) {
                    const uint4 Wf = Wlds[w8 + i][cl][l];
                    acc[i] = __builtin_amdgcn_mfma_f32_16x16x32_f16(
                        __builtin_bit_cast(half8, Wf),
                        __builtin_bit_cast(half8, B), acc[i], 0, 0, 0);
                }
            }
            B = Bn;
        }

        // tail: tanh(acc + xs) -> pack -> scatter into next B-frag buffer
        #pragma unroll
        for (int i = 0; i < 8; ++i) {
            const h2 xl = __builtin_bit_cast(h2, (u32)xq[i]);
            const h2 xh = __builtin_bit_cast(h2, (u32)(xq[i] >> 32));
            const float s0 = fast_tanh(acc[i].x + (float)xl.x);
            const float s1 = fast_tanh(acc[i].y + (float)xl.y);
            const float s2 = fast_tanh(acc[i].z + (float)xh.x);
            const float s3 = fast_tanh(acc[i].w + (float)xh.y);
            const int p0 = (w8 + i) * 16 + 4 * g;         // state col of s0
            const int ct = p0 >> 5, rem = p0 & 31;
            const int gp = rem >> 3, ds = (rem & 7) >> 1; // ds in {0,2}
            const u64 pk = (u64)packh2(s0, s1) | ((u64)packh2(s2, s3) << 32);
            *(u64*)((u32*)&Sst[nxt][ct][gp * 16 + r] + ds) = pk;
        }
        __syncthreads();
    }

    // epilogue: state(511) in Sst[0]; y[row] = state . Wd + bd
    {
        const int row = tid & 15, q = tid >> 4;   // q 0..15 -> k in [q*32, q*32+32)
        float part = 0.f;
        #pragma unroll
        for (int jp = 0; jp < 16; ++jp) {
            const int k = q * 32 + 2 * jp;
            const int c = k >> 5, kk = k & 31, gg = kk >> 3, dd = (kk & 7) >> 1;
            const u32 dw = ((const u32*)&Sst[0][c][gg * 16 + row])[dd];
            const h2 hv = __builtin_bit_cast(h2, dw);
            const float2 wd = *(const float2*)&Wd[k];
            part += (float)hv.x * wd.x + (float)hv.y * wd.y;
        }
        yp[row][q] = part;
        __syncthreads();
        if (tid < 16) {
            float s = 0.f;
            #pragma unroll
            for (int j = 0; j < 16; ++j) s += yp[tid][j];
            y[ring * 16 + tid] = s + bd[0];
        }
    }
}

// ---------------- fallback (proven R1 kernel, zero workspace) ----------------
#define KTOT 768
__global__ __launch_bounds__(256, 1)
void rnn_fused_f32(const int*   __restrict__ tokens,
                   const float* __restrict__ V,
                   const float* __restrict__ W,
                   const float* __restrict__ bias,
                   const float* __restrict__ Wd,
                   const float* __restrict__ bd,
                   float*       __restrict__ y)
{
    __shared__ float vcur[2][KTOT];
    __shared__ int   toks[2][SEQL];
    __shared__ float red0[4], red1[4];

    const int tid = threadIdx.x;
    const int c0 = tid * 2, c1 = c0 + 1;
    const int row0 = blockIdx.x * 2;

    for (int i = tid; i < 2 * SEQL; i += 256)
        toks[i >> 9][i & 511] = tokens[row0 * SEQL + i];
    vcur[0][EMBD + c0] = 0.f; vcur[0][EMBD + c1] = 0.f;
    vcur[1][EMBD + c0] = 0.f; vcur[1][EMBD + c1] = 0.f;
    __syncthreads();

    float emb0 = V[(long)toks[0][0] * EMBD + tid];
    float emb1 = V[(long)toks[1][0] * EMBD + tid];
    const float bh0 = bias[c0], bh1 = bias[c1];
    float s00 = 0.f, s01 = 0.f, s10 = 0.f, s11 = 0.f;

    for (int t = 0; t < SEQL; ++t) {
        vcur[0][tid] = emb0;
        vcur[1][tid] = emb1;
        __syncthreads();
        if (t + 1 < SEQL) {
            emb0 = V[(long)toks[0][t + 1] * EMBD + tid];
            emb1 = V[(long)toks[1][t + 1] * EMBD + tid];
        }
        float a000 = 0.f, a001 = 0.f, a010 = 0.f, a011 = 0.f;
        float a100 = 0.f, a101 = 0.f, a110 = 0.f, a111 = 0.f;
        const float* Wp = W + c0;
        #pragma unroll 4
        for (int k = 0; k < KTOT; k += 4) {
            const float4 v0 = *(const float4*)(&vcur[0][k]);
            const float4 v1 = *(const float4*)(&vcur[1][k]);
            const float2 w0 = *(const float2*)(Wp + (size_t)(k + 0) * HIDD);
            const float2 w1 = *(const float2*)(Wp + (size_t)(k + 1) * HIDD);
            const float2 w2 = *(const float2*)(Wp + (size_t)(k + 2) * HIDD);
            const float2 w3 = *(const float2*)(Wp + (size_t)(k + 3) * HIDD);
            a000 = fmaf(v0.x, w0.x, a000);  a001 = fmaf(v0.x, w0.y, a001);
            a010 = fmaf(v1.x, w0.x, a010);  a011 = fmaf(v1.x, w0.y, a011);
            a100 = fmaf(v0.y, w1.x, a100);  a101 = fmaf(v0.y, w1.y, a101);
            a110 = fmaf(v1.y, w1.x, a110);  a111 = fmaf(v1.y, w1.y, a111);
            a000 = fmaf(v0.z, w2.x, a000);  a001 = fmaf(v0.z, w2.y, a001);
            a010 = fmaf(v1.z, w2.x, a010);  a011 = fmaf(v1.z, w2.y, a011);
            a100 = fmaf(v0.w, w3.x, a100);  a101 = fmaf(v0.w, w3.y, a101);
            a110 = fmaf(v1.w, w3.x, a110);  a111 = fmaf(v1.w, w3.y, a111);
        }
        s00 = tanhf(bh0 + a000 + a100);
        s01 = tanhf(bh1 + a001 + a101);
        s10 = tanhf(bh0 + a010 + a110);
        s11 = tanhf(bh1 + a011 + a111);
        __syncthreads();
        vcur[0][EMBD + c0] = s00; vcur[0][EMBD + c1] = s01;
        vcur[1][EMBD + c0] = s10; vcur[1][EMBD + c1] = s11;
    }

    const float wd0 = Wd[c0], wd1 = Wd[c1];
    float q0 = s00 * wd0 + s01 * wd1;
    float q1 = s10 * wd0 + s11 * wd1;
    for (int off = 32; off > 0; off >>= 1) {
        q0 += __shfl_down(q0, off);
        q1 += __shfl_down(q1, off);
    }
    const int wv = tid >> 6, ln = tid & 63;
    if (ln == 0) { red0[wv] = q0; red1[wv] = q1; }
    __syncthreads();
    if (tid == 0) {
        const float bdv = bd[0];
        y[row0 + 0] = red0[0] + red0[1] + red0[2] + red0[3] + bdv;
        y[row0 + 1] = red1[0] + red1[1] + red1[2] + red1[3] + bdv;
    }
}

extern "C" void kernel_launch(void* const* d_in, const int* in_sizes, int n_in,
                              void* d_out, int out_size, void* d_ws, size_t ws_size,
                              hipStream_t stream)
{
    const int*   tokens = (const int*)  d_in[0];
    const float* V      = (const float*)d_in[1];
    const float* W      = (const float*)d_in[2];
    const float* b      = (const float*)d_in[3];
    const float* Wd     = (const float*)d_in[4];
    const float* bd     = (const float*)d_in[5];
    float* y = (float*)d_out;

    if (ws_size >= WS_NEED) {
        u32* WA = (u32*)((char*)d_ws + WS_WA_OFF);
        u64* XS = (u64*)((char*)d_ws + WS_XS_OFF);
        hipLaunchKernelGGL(convert_WA, dim3(768), dim3(256), 0, stream, W, WA);
        hipLaunchKernelGGL(xproj_gemm, dim3(4096), dim3(256), 0, stream, tokens, V, WA, b, XS);
        hipLaunchKernelGGL(rnn_fort2, dim3(8), dim3(256), 0, stream, WA, XS, Wd, bd, y);
    } else {
        hipLaunchKernelGGL(rnn_fused_f32, dim3(64), dim3(256), 0, stream,
                           tokens, V, W, b, Wd, bd, y);
    }
}

// Round 14
// 1257.854 us; speedup vs baseline: 1.6704x; 1.6704x over previous
//
#include <hip/hip_runtime.h>

#define EMBD 256
#define HIDD 512
#define SEQL 512

typedef unsigned int u32;
typedef unsigned long long u64;
typedef _Float16 half8 __attribute__((ext_vector_type(8)));
typedef _Float16 h2 __attribute__((ext_vector_type(2)));
typedef float f32x4 __attribute__((ext_vector_type(4)));

#define WS_WA_OFF 0                       // 786432 B : W A-frags [mt 0..31][chunk 0..23][64][4dw]
#define WS_XS_OFF 786432                  // 67108864 B : u64 xs[512 t][128 row][128] (f16 pairs, bias folded)
#define WS_NEED   (786432ull + 67108864ull)

static __device__ __forceinline__ u32 packh2(float a, float b) {
    _Float16 lo = (_Float16)a, hi = (_Float16)b;
    return (u32)__builtin_bit_cast(unsigned short, lo)
         | ((u32)__builtin_bit_cast(unsigned short, hi) << 16);
}

// tanh = 1 - 2/(e^{2x}+1): 5 VALU (mul, exp2, add, rcp, fma). Saturates right:
// x>>0 -> e=inf -> 1; x<<0 -> e=0 -> -1. No clamps needed.
static __device__ __forceinline__ float fast_tanh(float x) {
    const float e = __builtin_amdgcn_exp2f(x * 2.8853900817779268f);
    return __builtin_fmaf(-2.f, __builtin_amdgcn_rcpf(e + 1.f), 1.f);
}

// pack two f32 -> f16x2 dword in ONE instruction (v_cvt_pkrtz_f16_f32)
static __device__ __forceinline__ u32 pkrtz(float a, float b) {
    return __builtin_bit_cast(u32, __builtin_amdgcn_cvt_pkrtz(a, b));
}

// W (f32 [768][512]) -> A-frags for mfma_f32_16x16x32_f16.  [verified R10-R13]
__global__ __launch_bounds__(256)
void convert_WA(const float* __restrict__ W, u32* __restrict__ WA) {
    const int b = blockIdx.x;
    const int mt = b / 24, c = b % 24;
    const int tid = threadIdx.x, l = tid >> 2, d = tid & 3;
    const int k0 = 32 * c + 8 * (l >> 4) + 2 * d;
    const int hc = mt * 16 + (l & 15);
    WA[b * 256 + tid] = packh2(W[(size_t)k0 * HIDD + hc],
                               W[(size_t)(k0 + 1) * HIDD + hc]);
}

// xs[t][row][hcol] = (emb @ Wx)[hcol] + bias[hcol], f16 pairs.  [verified R12]
__global__ __launch_bounds__(256)
void xproj_gemm(const int*   __restrict__ tokens,
                const float* __restrict__ V,
                const u32*   __restrict__ WA,
                const float* __restrict__ bias,
                u64*         __restrict__ XS)
{
    const int wgid = blockIdx.x;
    const int t = wgid >> 3, rb = wgid & 7;
    const int w = threadIdx.x >> 6, l = threadIdx.x & 63;
    const int g = l >> 4;
    const int row = rb * 16 + (l & 15);

    const int tok = tokens[row * SEQL + t];
    const float* vb = V + (size_t)tok * EMBD;
    uint4 eb[8];
    #pragma unroll
    for (int c = 0; c < 8; ++c) {
        const float4 v1 = *(const float4*)&vb[32 * c + 8 * g];
        const float4 v2 = *(const float4*)&vb[32 * c + 8 * g + 4];
        eb[c].x = packh2(v1.x, v1.y); eb[c].y = packh2(v1.z, v1.w);
        eb[c].z = packh2(v2.x, v2.y); eb[c].w = packh2(v2.z, v2.w);
    }
    #pragma unroll
    for (int i = 0; i < 8; ++i) {
        const int hcb = w * 8 + i;
        f32x4 acc = (f32x4){0.f, 0.f, 0.f, 0.f};
        #pragma unroll
        for (int c = 0; c < 8; ++c) {
            const uint4 a = *(const uint4*)&WA[((hcb * 24 + c) * 64 + l) * 4];
            acc = __builtin_amdgcn_mfma_f32_16x16x32_f16(
                __builtin_bit_cast(half8, a), __builtin_bit_cast(half8, eb[c]),
                acc, 0, 0, 0);
        }
        const float4 b4 = *(const float4*)&bias[hcb * 16 + 4 * g];
        const u64 pk = (u64)packh2(acc.x + b4.x, acc.y + b4.y)
                     | ((u64)packh2(acc.z + b4.z, acc.w + b4.w) << 32);
        XS[(size_t)t * 16384 + (size_t)row * 128 + hcb * 4 + g] = pk;
    }
}

// Fortress v3: 8 WGs (ring = 16 rows) x 512 thr (8 waves, 2/SIMD).
// Wave w: M-tiles w*4..w*4+3, FULL K=512 (13 chunks in regs, 3 in LDS).
// 2-step-unrolled loop (static parity), B-frag prefetch, 5-instr tanh,
// cvt_pkrtz packing. 1 barrier/step. No inter-WG traffic.
__global__ __launch_bounds__(512, 1)
void rnn_fort3(const u32*   __restrict__ WA,
               const u64*   __restrict__ XS,
               const float* __restrict__ Wd,
               const float* __restrict__ bd,
               float*       __restrict__ y)
{
    __shared__ uint4 Wlds[32][3][64];   // 96 KB : state chunks 13..15 per mt
    __shared__ uint4 Sst[2][16][64];    // 32 KB : state B-frags, dbuf
    __shared__ float yp[16][33];

    const int tid = threadIdx.x, ring = blockIdx.x;
    const int w = tid >> 6, l = tid & 63, g = l >> 4, r = l & 15;
    const int w4 = w * 4;

    for (int i = tid; i < 32 * 3 * 64; i += 512) {
        const int mt = i / 192, rem = i % 192, cl = rem >> 6, l2 = rem & 63;
        Wlds[mt][cl][l2] = *(const uint4*)&WA[((mt * 24 + 21 + cl) * 64 + l2) * 4];
    }
    for (int i = tid; i < 2 * 16 * 64; i += 512)
        ((uint4*)Sst)[i] = (uint4){0u, 0u, 0u, 0u};

    // Wh register frags: state chunks 0..12 x 4 mt (208 regs, mostly AGPR)
    uint4 wreg[13][4];
    #pragma unroll
    for (int c = 0; c < 13; ++c)
        #pragma unroll
        for (int i = 0; i < 4; ++i)
            wreg[c][i] = *(const uint4*)&WA[(((w4 + i) * 24 + 8 + c) * 64 + l) * 4];

    // static per-thread addresses (loop-invariant)
    const uint4* const Bp[2]   = { &Sst[0][0][l], &Sst[1][0][l] };       // + c*64
    const uint4* const Wp      = &Wlds[w4][0][l];                        // + i*192 + cl*64
    u32* qp[2][4];                                                       // scatter slots
    #pragma unroll
    for (int i = 0; i < 4; ++i) {
        const int p0 = (w4 + i) * 16 + 4 * g;
        const int ct = p0 >> 5, rem = p0 & 31;
        const int gp = rem >> 3, ds = (rem & 7) >> 1;
        qp[0][i] = (u32*)&Sst[0][ct][gp * 16 + r] + ds;
        qp[1][i] = (u32*)&Sst[1][ct][gp * 16 + r] + ds;
    }
    const u64* xptr = XS + (size_t)(ring * 16 + r) * 128 + (w4 * 4 + g);

    __syncthreads();

// one recurrence step with compile-time parity CUR (reads Sst[CUR], writes Sst[1-CUR])
#define STEP(CUR)                                                                   \
    {                                                                               \
        u64 xq0 = xptr[0], xq1 = xptr[4], xq2 = xptr[8], xq3 = xptr[12];            \
        xptr += 16384;                                                              \
        f32x4 a0 = (f32x4){0.f,0.f,0.f,0.f}, a1 = a0, a2 = a0, a3 = a0;             \
        uint4 B = Bp[CUR][0];                                                       \
        _Pragma("unroll")                                                           \
        for (int c = 0; c < 16; ++c) {                                              \
            uint4 Bn;                                                               \
            if (c < 15) Bn = Bp[CUR][(c + 1) * 64];                                 \
            if (c < 13) {                                                           \
                a0 = __builtin_amdgcn_mfma_f32_16x16x32_f16(                        \
                    __builtin_bit_cast(half8, wreg[c][0]), __builtin_bit_cast(half8, B), a0, 0, 0, 0); \
                a1 = __builtin_amdgcn_mfma_f32_16x16x32_f16(                        \
                    __builtin_bit_cast(half8, wreg[c][1]), __builtin_bit_cast(half8, B), a1, 0, 0, 0); \
                a2 = __builtin_amdgcn_mfma_f32_16x16x32_f16(                        \
                    __builtin_bit_cast(half8, wreg[c][2]), __builtin_bit_cast(half8, B), a2, 0, 0, 0); \
                a3 = __builtin_amdgcn_mfma_f32_16x16x32_f16(                        \
                    __builtin_bit_cast(half8, wreg[c][3]), __builtin_bit_cast(half8, B), a3, 0, 0, 0); \
            } else {                                                                \
                const int cl = c - 13;                                              \
                a0 = __builtin_amdgcn_mfma_f32_16x16x32_f16(                        \
                    __builtin_bit_cast(half8, Wp[0 * 192 + cl * 64]), __builtin_bit_cast(half8, B), a0, 0, 0, 0); \
                a1 = __builtin_amdgcn_mfma_f32_16x16x32_f16(                        \
                    __builtin_bit_cast(half8, Wp[1 * 192 + cl * 64]), __builtin_bit_cast(half8, B), a1, 0, 0, 0); \
                a2 = __builtin_amdgcn_mfma_f32_16x16x32_f16(                        \
                    __builtin_bit_cast(half8, Wp[2 * 192 + cl * 64]), __builtin_bit_cast(half8, B), a2, 0, 0, 0); \
                a3 = __builtin_amdgcn_mfma_f32_16x16x32_f16(                        \
                    __builtin_bit_cast(half8, Wp[3 * 192 + cl * 64]), __builtin_bit_cast(half8, B), a3, 0, 0, 0); \
            }                                                                       \
            B = Bn;                                                                 \
        }                                                                           \
        _Pragma("unroll")                                                           \
        for (int i = 0; i < 4; ++i) {                                               \
            const f32x4 a = (i == 0) ? a0 : (i == 1) ? a1 : (i == 2) ? a2 : a3;     \
            const u64 xq  = (i == 0) ? xq0 : (i == 1) ? xq1 : (i == 2) ? xq2 : xq3; \
            const h2 xl = __builtin_bit_cast(h2, (u32)xq);                          \
            const h2 xh = __builtin_bit_cast(h2, (u32)(xq >> 32));                  \
            const float s0 = fast_tanh(a.x + (float)xl.x);                          \
            const float s1 = fast_tanh(a.y + (float)xl.y);                          \
            const float s2 = fast_tanh(a.z + (float)xh.x);                          \
            const float s3 = fast_tanh(a.w + (float)xh.y);                          \
            u32* q = qp[1 - CUR][i];                                                \
            q[0] = pkrtz(s0, s1);                                                   \
            q[1] = pkrtz(s2, s3);                                                   \
        }                                                                           \
        __syncthreads();                                                            \
    }

    for (int tt = 0; tt < SEQL / 2; ++tt) {
        STEP(0)
        STEP(1)
    }
#undef STEP

    // epilogue: state(511) in Sst[0]; y[row] = state . Wd + bd
    {
        const int row = tid & 15, q = tid >> 4;   // q 0..31 -> k in [q*16, +16)
        float part = 0.f;
        #pragma unroll
        for (int jp = 0; jp < 8; ++jp) {
            const int k = q * 16 + 2 * jp;
            const int c = k >> 5, kk = k & 31, gg = kk >> 3, dd = (kk & 7) >> 1;
            const u32 dw = ((const u32*)&Sst[0][c][gg * 16 + row])[dd];
            const h2 hv = __builtin_bit_cast(h2, dw);
            const float2 wd = *(const float2*)&Wd[k];
            part += (float)hv.x * wd.x + (float)hv.y * wd.y;
        }
        yp[row][q] = part;
        __syncthreads();
        if (tid < 16) {
            float s = 0.f;
            #pragma unroll
            for (int j = 0; j < 32; ++j) s += yp[tid][j];
            y[ring * 16 + tid] = s + bd[0];
        }
    }
}

// ---------------- fallback (proven R1 kernel, zero workspace) ----------------
#define KTOT 768
__global__ __launch_bounds__(256, 1)
void rnn_fused_f32(const int*   __restrict__ tokens,
                   const float* __restrict__ V,
                   const float* __restrict__ W,
                   const float* __restrict__ bias,
                   const float* __restrict__ Wd,
                   const float* __restrict__ bd,
                   float*       __restrict__ y)
{
    __shared__ float vcur[2][KTOT];
    __shared__ int   toks[2][SEQL];
    __shared__ float red0[4], red1[4];

    const int tid = threadIdx.x;
    const int c0 = tid * 2, c1 = c0 + 1;
    const int row0 = blockIdx.x * 2;

    for (int i = tid; i < 2 * SEQL; i += 256)
        toks[i >> 9][i & 511] = tokens[row0 * SEQL + i];
    vcur[0][EMBD + c0] = 0.f; vcur[0][EMBD + c1] = 0.f;
    vcur[1][EMBD + c0] = 0.f; vcur[1][EMBD + c1] = 0.f;
    __syncthreads();

    float emb0 = V[(long)toks[0][0] * EMBD + tid];
    float emb1 = V[(long)toks[1][0] * EMBD + tid];
    const float bh0 = bias[c0], bh1 = bias[c1];
    float s00 = 0.f, s01 = 0.f, s10 = 0.f, s11 = 0.f;

    for (int t = 0; t < SEQL; ++t) {
        vcur[0][tid] = emb0;
        vcur[1][tid] = emb1;
        __syncthreads();
        if (t + 1 < SEQL) {
            emb0 = V[(long)toks[0][t + 1] * EMBD + tid];
            emb1 = V[(long)toks[1][t + 1] * EMBD + tid];
        }
        float a000 = 0.f, a001 = 0.f, a010 = 0.f, a011 = 0.f;
        float a100 = 0.f, a101 = 0.f, a110 = 0.f, a111 = 0.f;
        const float* Wp = W + c0;
        #pragma unroll 4
        for (int k = 0; k < KTOT; k += 4) {
            const float4 v0 = *(const float4*)(&vcur[0][k]);
            const float4 v1 = *(const float4*)(&vcur[1][k]);
            const float2 w0 = *(const float2*)(Wp + (size_t)(k + 0) * HIDD);
            const float2 w1 = *(const float2*)(Wp + (size_t)(k + 1) * HIDD);
            const float2 w2 = *(const float2*)(Wp + (size_t)(k + 2) * HIDD);
            const float2 w3 = *(const float2*)(Wp + (size_t)(k + 3) * HIDD);
            a000 = fmaf(v0.x, w0.x, a000);  a001 = fmaf(v0.x, w0.y, a001);
            a010 = fmaf(v1.x, w0.x, a010);  a011 = fmaf(v1.x, w0.y, a011);
            a100 = fmaf(v0.y, w1.x, a100);  a101 = fmaf(v0.y, w1.y, a101);
            a110 = fmaf(v1.y, w1.x, a110);  a111 = fmaf(v1.y, w1.y, a111);
            a000 = fmaf(v0.z, w2.x, a000);  a001 = fmaf(v0.z, w2.y, a001);
            a010 = fmaf(v1.z, w2.x, a010);  a011 = fmaf(v1.z, w2.y, a011);
            a100 = fmaf(v0.w, w3.x, a100);  a101 = fmaf(v0.w, w3.y, a101);
            a110 = fmaf(v1.w, w3.x, a110);  a111 = fmaf(v1.w, w3.y, a111);
        }
        s00 = tanhf(bh0 + a000 + a100);
        s01 = tanhf(bh1 + a001 + a101);
        s10 = tanhf(bh0 + a010 + a110);
        s11 = tanhf(bh1 + a011 + a111);
        __syncthreads();
        vcur[0][EMBD + c0] = s00; vcur[0][EMBD + c1] = s01;
        vcur[1][EMBD + c0] = s10; vcur[1][EMBD + c1] = s11;
    }

    const float wd0 = Wd[c0], wd1 = Wd[c1];
    float q0 = s00 * wd0 + s01 * wd1;
    float q1 = s10 * wd0 + s11 * wd1;
    for (int off = 32; off > 0; off >>= 1) {
        q0 += __shfl_down(q0, off);
        q1 += __shfl_down(q1, off);
    }
    const int wv = tid >> 6, ln = tid & 63;
    if (ln == 0) { red0[wv] = q0; red1[wv] = q1; }
    __syncthreads();
    if (tid == 0) {
        const float bdv = bd[0];
        y[row0 + 0] = red0[0] + red0[1] + red0[2] + red0[3] + bdv;
        y[row0 + 1] = red1[0] + red1[1] + red1[2] + red1[3] + bdv;
    }
}

extern "C" void kernel_launch(void* const* d_in, const int* in_sizes, int n_in,
                              void* d_out, int out_size, void* d_ws, size_t ws_size,
                              hipStream_t stream)
{
    const int*   tokens = (const int*)  d_in[0];
    const float* V      = (const float*)d_in[1];
    const float* W      = (const float*)d_in[2];
    const float* b      = (const float*)d_in[3];
    const float* Wd     = (const float*)d_in[4];
    const float* bd     = (const float*)d_in[5];
    float* y = (float*)d_out;

    if (ws_size >= WS_NEED) {
        u32* WA = (u32*)((char*)d_ws + WS_WA_OFF);
        u64* XS = (u64*)((char*)d_ws + WS_XS_OFF);
        hipLaunchKernelGGL(convert_WA, dim3(768), dim3(256), 0, stream, W, WA);
        hipLaunchKernelGGL(xproj_gemm, dim3(4096), dim3(256), 0, stream, tokens, V, WA, b, XS);
        hipLaunchKernelGGL(rnn_fort3, dim3(8), dim3(512), 0, stream, WA, XS, Wd, bd, y);
    } else {
        hipLaunchKernelGGL(rnn_fused_f32, dim3(64), dim3(256), 0, stream,
                           tokens, V, W, b, Wd, bd, y);
    }
}